// Round 7
// baseline (227.289 us; speedup 1.0000x reference)
//
#include <hip/hip_runtime.h>
#include <hip/hip_bf16.h>

#define B_ 4
#define N_ 512
#define F_ 128
#define K_ 32
#define TPB 528   // unordered 16x16 chunk-pair tiles per batch: 32*33/2

typedef __attribute__((ext_vector_type(8))) short short8;   // bf16x8 MFMA operand
typedef __attribute__((ext_vector_type(4))) float f32x4;    // MFMA accumulator

__device__ __forceinline__ unsigned cvt_pk_bf16(float a, float b) {
  unsigned r;
  asm("v_cvt_pk_bf16_f32 %0, %1, %2" : "=v"(r) : "v"(a), "v"(b));
  return r;
}
__device__ __forceinline__ float exp2_hw(float x) {
  float r; asm("v_exp_f32 %0, %1" : "=v"(r) : "v"(x)); return r;
}
__device__ __forceinline__ float exp2_neg_hw(float x) {   // 2^(-x)
  float r; asm("v_exp_f32 %0, -%1" : "=v"(r) : "v"(x)); return r;
}
__device__ __forceinline__ float log2_hw(float x) {
  float r; asm("v_log_f32 %0, %1" : "=v"(r) : "v"(x)); return r;
}

// softplus(u) - ln2 = max(u,0) + ln2 * log2(0.5 + 0.5*exp2(-|u|*log2e))
__device__ __forceinline__ float sspb(float u) {
  float e = exp2_hw(__builtin_fabsf(u) * -1.4426950408889634f);
  float l = log2_hw(fmaf(e, 0.5f, 0.5f));
  return fmaf(l, 0.6931471805599453f, fmaxf(u, 0.f));
}

// x[row][f] = emb[row]@Ww^T + Wb; also out[row] = emb[row] (init for atomics)
__global__ void xw_kernel(const float* __restrict__ emb, const float* __restrict__ Ww,
                          const float* __restrict__ Wb, float* __restrict__ x,
                          float* __restrict__ out) {
  __shared__ float erow[F_];
  int row = blockIdx.x;
  int f = threadIdx.x;
  float ev = emb[row * F_ + f];
  erow[f] = ev;
  out[row * F_ + f] = ev;
  __syncthreads();
  const float4* w4 = (const float4*)(Ww + f * F_);
  float acc = 0.f;
#pragma unroll 8
  for (int g4 = 0; g4 < F_ / 4; ++g4) {
    float4 wv = w4[g4];
    acc = fmaf(erow[g4 * 4 + 0], wv.x, acc);
    acc = fmaf(erow[g4 * 4 + 1], wv.y, acc);
    acc = fmaf(erow[g4 * 4 + 2], wv.z, acc);
    acc = fmaf(erow[g4 * 4 + 3], wv.w, acc);
  }
  x[row * F_ + f] = acc + Wb[f];
}

// Symmetric pair-tile kernel: block = (b, chunk a, chunk c), a<=c, chunks of 16 rows.
// Computes Wf once per unordered pair; scatters to out[i] and (off-diag) out[j].
__launch_bounds__(256, 4)
__global__ void pair_kernel(const float* __restrict__ coords,
                            const float* __restrict__ w1, const float* __restrict__ b1,
                            const float* __restrict__ w2, const float* __restrict__ b2,
                            const float* __restrict__ x, float* __restrict__ out) {
  __shared__ float dtile[16][16];                 // pair distances
  __shared__ __align__(16) short rbuf[16][40];    // rbf [j][k], padded rows (80B)
  __shared__ __align__(16) short h1s[16 * F_];    // h1 [j][f1], XOR-swizzled
  __shared__ float b1s[F_], b2s[F_];

  const int blk = blockIdx.x;
  const int b = blk / TPB;
  const int t = blk - b * TPB;
  // decode t -> (a, c), a<=c: offset(a) = 32a - a(a-1)/2
  int a = (int)(32.5f - sqrtf(32.5f * 32.5f - 2.0f * (float)t));
  while (32 * (a + 1) - ((a + 1) * a) / 2 <= t) ++a;
  while (32 * a - (a * (a - 1)) / 2 > t) --a;
  const int c = a + (t - (32 * a - (a * (a - 1)) / 2));
  const bool diag = (a == c);
  const int rowI = b * N_ + a * 16;               // i-rows (iterated)
  const int rowJ = b * N_ + c * 16;               // j-cols (MFMA columns)

  const int tid = threadIdx.x;
  const int lane = tid & 63, W = tid >> 6;        // 4 waves; wave owns 32 channels
  const int l15 = lane & 15, lg = lane >> 4;
  const int fbase = W << 5;

  // ---- distances (one per thread) ----
  {
    int i = tid >> 4, j = tid & 15;
    const float* ci = coords + (rowI + i) * 3;
    const float* cj = coords + (rowJ + j) * 3;
    float dx = ci[0] - cj[0], dy = ci[1] - cj[1], dz = ci[2] - cj[2];
    dtile[i][j] = sqrtf(fmaf(dx, dx, fmaf(dy, dy, fmaf(dz, dz, 1e-12f))));
  }
  if (tid < F_) { b1s[tid] = b1[tid]; b2s[tid] = b2[tid]; }

  // ---- weight A-fragments from global (L2-hot) ----
  short8 bw1[2], w2f[2][4];
#pragma unroll
  for (int gf = 0; gf < 2; ++gf) {
    int f1 = fbase + gf * 16 + l15;
    unsigned pk[4];
#pragma unroll
    for (int p = 0; p < 4; ++p)
      pk[p] = cvt_pk_bf16(w1[(lg * 8 + 2 * p) * F_ + f1], w1[(lg * 8 + 2 * p + 1) * F_ + f1]);
    bw1[gf] = *(short8*)pk;
#pragma unroll
    for (int kk = 0; kk < 4; ++kk) {
      unsigned qk[4];
#pragma unroll
      for (int p = 0; p < 4; ++p)
        qk[p] = cvt_pk_bf16(w2[(kk * 32 + lg * 8 + 2 * p) * F_ + f1],
                            w2[(kk * 32 + lg * 8 + 2 * p + 1) * F_ + f1]);
      w2f[gf][kk] = *(short8*)qk;
    }
  }
  __syncthreads();

  f32x4 b1v[2], b2v[2];
  float xj[2][4];
#pragma unroll
  for (int gf = 0; gf < 2; ++gf) {
    int f0 = fbase + gf * 16 + lg * 4;
    b1v[gf] = *(const f32x4*)&b1s[f0];
    b2v[gf] = *(const f32x4*)&b2s[f0];
    float4 xv = *(const float4*)&x[(rowJ + l15) * F_ + f0];   // loop-invariant (col j = l15)
    xj[gf][0] = xv.x; xj[gf][1] = xv.y; xj[gf][2] = xv.z; xj[gf][3] = xv.w;
  }

  const float S_ = 3.798282f;                    // sqrt(10*log2e)
  const float DS = (5.0f / 31.0f) * 3.798282f;
  float outJ[2][4] = {{0.f,0.f,0.f,0.f},{0.f,0.f,0.f,0.f}};

#pragma unroll 1
  for (int i = 0; i < 16; ++i) {
    // ---- phase A: cooperative rbf for row i -> rbuf[j][k] ----
    {
      int j = tid >> 4, k2 = (tid & 15) * 2;
      float d = dtile[i][j];
      float u0 = fmaf(d, S_, -(float)k2 * DS);
      float u1 = u0 - DS;
      float e0 = exp2_neg_hw(u0 * u0);
      float e1 = exp2_neg_hw(u1 * u1);
      *(unsigned*)&rbuf[j][k2] = cvt_pk_bf16(e0, e1);
    }
    __syncthreads();   // rbuf ready (also orders vs prev iter's h1s reads)

    // ---- phase B: h1 = ssp(w1^T @ rbf^T + b1) -> h1s ----
    short8 rb = *(const short8*)&rbuf[l15][lg * 8];
#pragma unroll
    for (int gf = 0; gf < 2; ++gf) {
      f32x4 acc = __builtin_amdgcn_mfma_f32_16x16x32_bf16(bw1[gf], rb, b1v[gf], 0, 0, 0);
      int g0b = (fbase + gf * 16 + lg * 4) * 2;
      unsigned lo = cvt_pk_bf16(sspb(acc[0]), sspb(acc[1]));
      unsigned hi = cvt_pk_bf16(sspb(acc[2]), sspb(acc[3]));
      uint2 val = {lo, hi};
      *(uint2*)((char*)h1s + l15 * 256 + (g0b ^ ((l15 & 7) << 4))) = val;
    }
    __syncthreads();   // h1 ready

    // ---- phase C: Wf = ssp(w2^T @ h1^T + b2); scatter both sides ----
    f32x4 accD[2] = {b2v[0], b2v[1]};
#pragma unroll
    for (int kk = 0; kk < 4; ++kk) {
      short8 hfr = *(const short8*)((const char*)h1s +
                    l15 * 256 + ((kk * 64 + lg * 16) ^ ((l15 & 7) << 4)));
#pragma unroll
      for (int gf = 0; gf < 2; ++gf)
        accD[gf] = __builtin_amdgcn_mfma_f32_16x16x32_bf16(w2f[gf][kk], hfr, accD[gf], 0, 0, 0);
    }

    const float msk = (diag && (l15 == i)) ? 0.f : 1.f;
    float wv[2][4];
#pragma unroll
    for (int gf = 0; gf < 2; ++gf)
#pragma unroll
      for (int jj = 0; jj < 4; ++jj)
        wv[gf][jj] = msk * sspb(accD[gf][jj]);

    // n-side: out[rowI+i][f] += sum_j Wf[f][j]*x[rowJ+j][f]  (reduce over l15)
#pragma unroll
    for (int gf = 0; gf < 2; ++gf) {
#pragma unroll
      for (int jj = 0; jj < 4; ++jj) {
        float v = wv[gf][jj] * xj[gf][jj];
        v += __shfl_xor(v, 1);
        v += __shfl_xor(v, 2);
        v += __shfl_xor(v, 4);
        v += __shfl_xor(v, 8);
        if (l15 == 0)
          unsafeAtomicAdd(&out[(rowI + i) * F_ + fbase + gf * 16 + lg * 4 + jj], v);
      }
    }

    // m-side: out[rowJ+j][f] += Wf[f][j]*x[rowI+i][f]  (register accum; skip on diag)
    if (!diag) {
#pragma unroll
      for (int gf = 0; gf < 2; ++gf) {
        float4 xi = *(const float4*)&x[(rowI + i) * F_ + fbase + gf * 16 + lg * 4];
        outJ[gf][0] = fmaf(wv[gf][0], xi.x, outJ[gf][0]);
        outJ[gf][1] = fmaf(wv[gf][1], xi.y, outJ[gf][1]);
        outJ[gf][2] = fmaf(wv[gf][2], xi.z, outJ[gf][2]);
        outJ[gf][3] = fmaf(wv[gf][3], xi.w, outJ[gf][3]);
      }
    }
  }

  // ---- m-side flush ----
  if (!diag) {
#pragma unroll
    for (int gf = 0; gf < 2; ++gf)
#pragma unroll
      for (int jj = 0; jj < 4; ++jj)
        unsafeAtomicAdd(&out[(rowJ + l15) * F_ + fbase + gf * 16 + lg * 4 + jj], outJ[gf][jj]);
  }
}

extern "C" void kernel_launch(void* const* d_in, const int* in_sizes, int n_in,
                              void* d_out, int out_size, void* d_ws, size_t ws_size,
                              hipStream_t stream) {
  const float* coords = (const float*)d_in[0];
  const float* emb    = (const float*)d_in[1];
  // d_in[2] = rbf_centers (linspace(0,5,32), recomputed inline)
  const float* w1 = (const float*)d_in[3];
  const float* b1 = (const float*)d_in[4];
  const float* w2 = (const float*)d_in[5];
  const float* b2 = (const float*)d_in[6];
  const float* Ww = (const float*)d_in[7];
  const float* Wb = (const float*)d_in[8];
  float* out = (float*)d_out;
  float* x   = (float*)d_ws;                 // B*N*F fp32 = 1 MiB scratch

  hipLaunchKernelGGL(xw_kernel, dim3(B_ * N_), dim3(F_), 0, stream, emb, Ww, Wb, x, out);
  hipLaunchKernelGGL(pair_kernel, dim3(B_ * TPB), dim3(256), 0, stream,
                     coords, w1, b1, w2, b2, x, out);
}

// Round 8
// 154.786 us; speedup vs baseline: 1.4684x; 1.4684x over previous
//
#include <hip/hip_runtime.h>
#include <hip/hip_bf16.h>

#define B_ 4
#define N_ 512
#define F_ 128
#define K_ 32
#define NPAIR 136   // 16 chunks of 32 rows: 16*17/2 unordered pairs

typedef __attribute__((ext_vector_type(8))) short short8;   // bf16x8 MFMA operand
typedef __attribute__((ext_vector_type(4))) float f32x4;    // MFMA accumulator

__device__ __forceinline__ unsigned cvt_pk_bf16(float a, float b) {
  unsigned r;
  asm("v_cvt_pk_bf16_f32 %0, %1, %2" : "=v"(r) : "v"(a), "v"(b));
  return r;
}
__device__ __forceinline__ float exp2_hw(float x) {
  float r; asm("v_exp_f32 %0, %1" : "=v"(r) : "v"(x)); return r;
}
__device__ __forceinline__ float exp2_neg_hw(float x) {   // 2^(-x)
  float r; asm("v_exp_f32 %0, -%1" : "=v"(r) : "v"(x)); return r;
}
__device__ __forceinline__ float log2_hw(float x) {
  float r; asm("v_log_f32 %0, %1" : "=v"(r) : "v"(x)); return r;
}

// softplus(u) - ln2 = max(u,0) + ln2 * log2(0.5 + 0.5*exp2(-|u|*log2e))
__device__ __forceinline__ float sspb(float u) {
  float e = exp2_hw(__builtin_fabsf(u) * -1.4426950408889634f);
  float l = log2_hw(fmaf(e, 0.5f, 0.5f));
  return fmaf(l, 0.6931471805599453f, fmaxf(u, 0.f));
}

// x[row][f] = emb[row]@Ww^T + Wb; also out[row] = emb[row] (init for atomics)
__global__ void xw_kernel(const float* __restrict__ emb, const float* __restrict__ Ww,
                          const float* __restrict__ Wb, float* __restrict__ x,
                          float* __restrict__ out) {
  __shared__ float erow[F_];
  int row = blockIdx.x;
  int f = threadIdx.x;
  float ev = emb[row * F_ + f];
  erow[f] = ev;
  out[row * F_ + f] = ev;
  __syncthreads();
  const float4* w4 = (const float4*)(Ww + f * F_);
  float acc = 0.f;
#pragma unroll 8
  for (int g4 = 0; g4 < F_ / 4; ++g4) {
    float4 wv = w4[g4];
    acc = fmaf(erow[g4 * 4 + 0], wv.x, acc);
    acc = fmaf(erow[g4 * 4 + 1], wv.y, acc);
    acc = fmaf(erow[g4 * 4 + 2], wv.z, acc);
    acc = fmaf(erow[g4 * 4 + 3], wv.w, acc);
  }
  x[row * F_ + f] = acc + Wb[f];
}

// Symmetric pair-chunk kernel with the R5 body geometry.
// Block = (b, unordered pair (a<=c) of 32-row chunks, i-half of 16 rows).
// 16 iterations; per iter: Wf[128 f][32 j] for one i via transposed MFMA.
__launch_bounds__(256, 3)
__global__ void pair_kernel(const float* __restrict__ coords,
                            const float* __restrict__ w1, const float* __restrict__ b1,
                            const float* __restrict__ w2, const float* __restrict__ b2,
                            const float* __restrict__ x, float* __restrict__ out) {
  __shared__ float dtile[16][32];                       // 2 KB distances
  __shared__ __align__(16) short hbuf[2][32 * F_];      // h1 dbuf, XOR-swizzled, 16 KB
  __shared__ float b1s[F_], b2s[F_];

  const int blk = blockIdx.x;
  const int b = blk / (NPAIR * 2);
  int r = blk - b * (NPAIR * 2);
  const int half = r & 1;
  const int t = r >> 1;
  // decode t -> (a, c), a<=c among 16 chunks: cum(a) = 16a - a(a-1)/2
  int a = (int)(16.5f - sqrtf(16.5f * 16.5f - 2.0f * (float)t));
  while (16 * (a + 1) - ((a + 1) * a) / 2 <= t) ++a;
  while (16 * a - (a * (a - 1)) / 2 > t) --a;
  const int c = a + (t - (16 * a - (a * (a - 1)) / 2));
  const bool diag = (a == c);
  const int rowI = b * N_ + a * 32 + half * 16;         // 16 i-rows
  const int rowJ = b * N_ + c * 32;                     // 32 j-cols

  const int tid = threadIdx.x;
  const int lane = tid & 63, W = tid >> 6;              // 4 waves x 32 channels
  const int l15 = lane & 15, lg = lane >> 4;
  const int fbase = W << 5;

  // ---- distances i x j (2 per thread) ----
  for (int idx = tid; idx < 512; idx += 256) {
    int i = idx >> 5, j = idx & 31;
    const float* ci = coords + (rowI + i) * 3;
    const float* cj = coords + (rowJ + j) * 3;
    float dx = ci[0] - cj[0], dy = ci[1] - cj[1], dz = ci[2] - cj[2];
    dtile[i][j] = sqrtf(fmaf(dx, dx, fmaf(dy, dy, fmaf(dz, dz, 1e-12f))));
  }
  if (tid < F_) { b1s[tid] = b1[tid]; b2s[tid] = b2[tid]; }

  // ---- weight A-fragments from global (L2-hot) ----
  short8 bw1[2], w2f[2][4];
#pragma unroll
  for (int gf = 0; gf < 2; ++gf) {
    int f1 = fbase + gf * 16 + l15;
    unsigned pk[4];
#pragma unroll
    for (int p = 0; p < 4; ++p)
      pk[p] = cvt_pk_bf16(w1[(lg * 8 + 2 * p) * F_ + f1], w1[(lg * 8 + 2 * p + 1) * F_ + f1]);
    bw1[gf] = *(short8*)pk;
#pragma unroll
    for (int kk = 0; kk < 4; ++kk) {
      unsigned qk[4];
#pragma unroll
      for (int p = 0; p < 4; ++p)
        qk[p] = cvt_pk_bf16(w2[(kk * 32 + lg * 8 + 2 * p) * F_ + f1],
                            w2[(kk * 32 + lg * 8 + 2 * p + 1) * F_ + f1]);
      w2f[gf][kk] = *(short8*)qk;
    }
  }
  __syncthreads();

  f32x4 b1v[2], b2v[2];
  float xj[2][2][4];                                    // x[rowJ + j][f], loop-invariant
#pragma unroll
  for (int gf = 0; gf < 2; ++gf) {
    int f0 = fbase + gf * 16 + lg * 4;
    b1v[gf] = *(const f32x4*)&b1s[f0];
    b2v[gf] = *(const f32x4*)&b2s[f0];
#pragma unroll
    for (int mf = 0; mf < 2; ++mf) {
      float4 xv = *(const float4*)&x[(rowJ + mf * 16 + l15) * F_ + f0];
      xj[gf][mf][0] = xv.x; xj[gf][mf][1] = xv.y;
      xj[gf][mf][2] = xv.z; xj[gf][mf][3] = xv.w;
    }
  }

  const float S_ = 3.798282f;                           // sqrt(10*log2e)
  const float DS = (5.0f / 31.0f) * 3.798282f;
  const float c0s = (float)(lg * 8) * DS;

  float outJ[2][2][4] = {{{0.f,0.f,0.f,0.f},{0.f,0.f,0.f,0.f}},
                         {{0.f,0.f,0.f,0.f},{0.f,0.f,0.f,0.f}}};

#pragma unroll 1
  for (int i = 0; i < 16; ++i) {
    short* hb = hbuf[i & 1];

    // ---- rbf B-frags for row i (col j = mf*16+l15, k = lg*8+p) ----
    short8 rb[2];
#pragma unroll
    for (int mf = 0; mf < 2; ++mf) {
      int jl = mf * 16 + l15;
      float d = dtile[i][jl];
      float dsc = fmaf(d, S_, -c0s);
      unsigned pk[4];
#pragma unroll
      for (int p = 0; p < 4; ++p) {
        float t0 = dsc - (float)(2 * p) * DS;
        float t1 = dsc - (float)(2 * p + 1) * DS;
        float e0 = exp2_neg_hw(t0 * t0);
        float e1 = exp2_neg_hw(t1 * t1);
        pk[p] = cvt_pk_bf16(e0, e1);
      }
      rb[mf] = *(short8*)pk;
    }

    // ---- h1 = ssp(w1^T @ rbf^T + b1) -> LDS (bf16, swizzled) ----
#pragma unroll
    for (int gf = 0; gf < 2; ++gf)
#pragma unroll
      for (int mf = 0; mf < 2; ++mf) {
        f32x4 acc = __builtin_amdgcn_mfma_f32_16x16x32_bf16(bw1[gf], rb[mf], b1v[gf], 0, 0, 0);
        int m_loc = mf * 16 + l15;
        int g0b = (fbase + gf * 16 + lg * 4) * 2;
        unsigned lo = cvt_pk_bf16(sspb(acc[0]), sspb(acc[1]));
        unsigned hi = cvt_pk_bf16(sspb(acc[2]), sspb(acc[3]));
        uint2 val = {lo, hi};
        *(uint2*)((char*)hb + m_loc * 256 + (g0b ^ ((m_loc & 7) << 4))) = val;
      }
    __syncthreads();   // h1 ready (dbuf covers WAR with previous iter's reads)

    // ---- Wf_pre = w2^T @ h1^T + b2 ----
    f32x4 accD[2][2];
#pragma unroll
    for (int gf = 0; gf < 2; ++gf) { accD[gf][0] = b2v[gf]; accD[gf][1] = b2v[gf]; }
#pragma unroll
    for (int kk = 0; kk < 4; ++kk) {
      short8 hfr[2];
#pragma unroll
      for (int mf = 0; mf < 2; ++mf) {
        int row = mf * 16 + l15;
        hfr[mf] = *(const short8*)((const char*)hb +
                   row * 256 + ((kk * 64 + lg * 16) ^ ((row & 7) << 4)));
      }
#pragma unroll
      for (int gf = 0; gf < 2; ++gf)
#pragma unroll
        for (int mf = 0; mf < 2; ++mf)
          accD[gf][mf] = __builtin_amdgcn_mfma_f32_16x16x32_bf16(w2f[gf][kk], hfr[mf], accD[gf][mf], 0, 0, 0);
    }

    // ---- Wf = ssp(accD), self-mask ----
    float wv[2][2][4];
#pragma unroll
    for (int mf = 0; mf < 2; ++mf) {
      int jl = mf * 16 + l15;
      float msk = (diag && (jl == half * 16 + i)) ? 0.f : 1.f;
#pragma unroll
      for (int gf = 0; gf < 2; ++gf)
#pragma unroll
        for (int jj = 0; jj < 4; ++jj)
          wv[gf][mf][jj] = msk * sspb(accD[gf][mf][jj]);
    }

    // ---- n-side: out[rowI+i][f] += sum_j wv[f][j]*x[rowJ+j][f] ----
    float p0[2][4];
#pragma unroll
    for (int gf = 0; gf < 2; ++gf)
#pragma unroll
      for (int jj = 0; jj < 4; ++jj)
        p0[gf][jj] = fmaf(wv[gf][0][jj], xj[gf][0][jj], wv[gf][1][jj] * xj[gf][1][jj]);
#pragma unroll
    for (int d = 1; d <= 8; d <<= 1)
#pragma unroll
      for (int gf = 0; gf < 2; ++gf)
#pragma unroll
        for (int jj = 0; jj < 4; ++jj)
          p0[gf][jj] += __shfl_xor(p0[gf][jj], d);
    if (l15 == 0) {
      int ro = (rowI + i) * F_ + fbase + lg * 4;
#pragma unroll
      for (int gf = 0; gf < 2; ++gf)
#pragma unroll
        for (int jj = 0; jj < 4; ++jj)
          unsafeAtomicAdd(&out[ro + gf * 16 + jj], p0[gf][jj]);
    }

    // ---- m-side: outJ[f][j] += wv[f][j]*x[rowI+i][f] (register accum) ----
    if (!diag) {
#pragma unroll
      for (int gf = 0; gf < 2; ++gf) {
        float4 xi = *(const float4*)&x[(rowI + i) * F_ + fbase + gf * 16 + lg * 4];
#pragma unroll
        for (int mf = 0; mf < 2; ++mf) {
          outJ[gf][mf][0] = fmaf(wv[gf][mf][0], xi.x, outJ[gf][mf][0]);
          outJ[gf][mf][1] = fmaf(wv[gf][mf][1], xi.y, outJ[gf][mf][1]);
          outJ[gf][mf][2] = fmaf(wv[gf][mf][2], xi.z, outJ[gf][mf][2]);
          outJ[gf][mf][3] = fmaf(wv[gf][mf][3], xi.w, outJ[gf][mf][3]);
        }
      }
    }
  }

  // ---- m-side flush ----
  if (!diag) {
#pragma unroll
    for (int mf = 0; mf < 2; ++mf) {
      int ro = (rowJ + mf * 16 + l15) * F_ + fbase + lg * 4;
#pragma unroll
      for (int gf = 0; gf < 2; ++gf)
#pragma unroll
        for (int jj = 0; jj < 4; ++jj)
          unsafeAtomicAdd(&out[ro + gf * 16 + jj], outJ[gf][mf][jj]);
    }
  }
}

extern "C" void kernel_launch(void* const* d_in, const int* in_sizes, int n_in,
                              void* d_out, int out_size, void* d_ws, size_t ws_size,
                              hipStream_t stream) {
  const float* coords = (const float*)d_in[0];
  const float* emb    = (const float*)d_in[1];
  // d_in[2] = rbf_centers (linspace(0,5,32), recomputed inline)
  const float* w1 = (const float*)d_in[3];
  const float* b1 = (const float*)d_in[4];
  const float* w2 = (const float*)d_in[5];
  const float* b2 = (const float*)d_in[6];
  const float* Ww = (const float*)d_in[7];
  const float* Wb = (const float*)d_in[8];
  float* out = (float*)d_out;
  float* x   = (float*)d_ws;                 // B*N*F fp32 = 1 MiB scratch

  hipLaunchKernelGGL(xw_kernel, dim3(B_ * N_), dim3(F_), 0, stream, emb, Ww, Wb, x, out);
  hipLaunchKernelGGL(pair_kernel, dim3(B_ * NPAIR * 2), dim3(256), 0, stream,
                     coords, w1, b1, w2, b2, x, out);
}